// Round 9
// baseline (200.566 us; speedup 1.0000x reference)
//
#include <hip/hip_runtime.h>
#include <hip/hip_bf16.h>

typedef __attribute__((ext_vector_type(8))) short short8;  // 8 bf16 (4 VGPRs)
typedef __attribute__((ext_vector_type(4))) short short4v;
typedef __attribute__((ext_vector_type(4))) float f32x4;
typedef __attribute__((ext_vector_type(2))) float f32x2;

// ---------------------------------------------------------------------------
// prep: fp32 -> bf16, exact fp32 row norms. 16 lanes per row, float4 loads.
// ---------------------------------------------------------------------------
__global__ __launch_bounds__(256) void ahd_prep(
    const float* __restrict__ s1, const float* __restrict__ s2,
    __hip_bfloat16* __restrict__ abf, __hip_bfloat16* __restrict__ bbf,
    float* __restrict__ x2, float* __restrict__ y2,
    int N, int M)
{
    const int t   = blockIdx.x * 256 + threadIdx.x;
    const int row = t >> 4;
    const int sub = t & 15;

    const float* src; __hip_bfloat16* dst; float* nrm; int r;
    if (row < N)            { src = s1; dst = abf; nrm = x2; r = row; }
    else if (row < N + M)   { src = s2; dst = bbf; nrm = y2; r = row - N; }
    else return;

    const float4 v = *(const float4*)&src[(size_t)r * 64 + sub * 4];
    __hip_bfloat16 h0 = __float2bfloat16(v.x), h1 = __float2bfloat16(v.y);
    __hip_bfloat16 h2 = __float2bfloat16(v.z), h3 = __float2bfloat16(v.w);
    short4v sv = { *(short*)&h0, *(short*)&h1, *(short*)&h2, *(short*)&h3 };
    *(short4v*)&dst[(size_t)r * 64 + sub * 4] = sv;

    float ss = v.x * v.x + v.y * v.y + v.z * v.z + v.w * v.w;
    ss += __shfl_xor(ss, 1);
    ss += __shfl_xor(ss, 2);
    ss += __shfl_xor(ss, 4);
    ss += __shfl_xor(ss, 8);
    if (sub == 0) nrm[r] = ss;
}

// ---------------------------------------------------------------------------
// fused distance-GEMM + row/col min partials. Pure dataflow: no LDS, no
// barriers, no atomics, no rotation copies (round-8 lesson: VALU-issue time
// ~50 µs in every structure from staging/rotation/addr overhead; latency
// chains through LDS+barriers killed packing). Block (rb,cb) = 128x128 tile;
// wave w independently owns rows w*32..+32 x all 128 cols. A-frags (4) and
// all 16 B-frags loaded from global (L2/L3-hot) upfront -- one latency
// exposure per wave. Then 8x {4 MFMA + fused pk epilogue}. Partials stored
// plain: rpart[rb][cb][128], cpart[cb][rb][wave][128]; reduce finishes.
// ---------------------------------------------------------------------------
__global__ __launch_bounds__(256) void ahd_gemm(
    const __hip_bfloat16* __restrict__ abf, const __hip_bfloat16* __restrict__ bbf,
    const float* __restrict__ x2, const float* __restrict__ y2,
    float* __restrict__ rpart, float* __restrict__ cpart,
    int nrb, int ncb)
{
    const int tid  = threadIdx.x;
    const int lane = tid & 63;
    const int w    = tid >> 6;
    const int lr   = lane & 15, lh = lane >> 4;

    const int rb = blockIdx.x, cb = blockIdx.y;
    const int wrow = rb * 128 + w * 32;     // this wave's first row
    const int bcol = cb * 128;

    // ---- A fragments from global: afr[ks][m] = A[wrow+m*16+lr][ks*32+lh*8..]
    const char* aB = (const char*)abf + ((size_t)(wrow + lr)) * 128 + lh * 16;
    short8 afr[2][2];
    #pragma unroll
    for (int ks = 0; ks < 2; ++ks)
        #pragma unroll
        for (int m = 0; m < 2; ++m)
            afr[ks][m] = *(const short8*)(aB + m * 2048 + ks * 64);

    // ---- all 16 B fragments upfront: bq[n][ks] = B[bcol+n*16+lr][ks*32+lh*8..]
    const char* bB = (const char*)bbf + ((size_t)(bcol + lr)) * 128 + lh * 16;
    short8 bq[8][2];
    #pragma unroll
    for (int n = 0; n < 8; ++n)
        #pragma unroll
        for (int ks = 0; ks < 2; ++ks)
            bq[n][ks] = *(const short8*)(bB + n * 2048 + ks * 64);

    // ---- norms
    f32x2 xq[2][2];   // [m][jp]
    #pragma unroll
    for (int m = 0; m < 2; ++m) {
        const f32x4 xv = *(const f32x4*)&x2[wrow + m * 16 + lh * 4];
        xq[m][0] = (f32x2){xv[0], xv[1]};
        xq[m][1] = (f32x2){xv[2], xv[3]};
    }
    float yv[8];
    #pragma unroll
    for (int n = 0; n < 8; ++n)
        yv[n] = y2[bcol + n * 16 + lr];

    const f32x4 ZERO = {0.f, 0.f, 0.f, 0.f};
    const f32x2 mm2  = {-2.f, -2.f};

    f32x2 rowm[2][2];
    #pragma unroll
    for (int m = 0; m < 2; ++m)
        #pragma unroll
        for (int jp = 0; jp < 2; ++jp) rowm[m][jp] = (f32x2){1e30f, 1e30f};
    float colm[8];

    // ---- 8 x {4 MFMA into transient acc, fused epilogue}
    #pragma unroll
    for (int n = 0; n < 8; ++n) {
        f32x4 a0 = __builtin_amdgcn_mfma_f32_16x16x32_bf16(afr[0][0], bq[n][0], ZERO, 0, 0, 0);
        f32x4 a1 = __builtin_amdgcn_mfma_f32_16x16x32_bf16(afr[0][1], bq[n][0], ZERO, 0, 0, 0);
        a0 = __builtin_amdgcn_mfma_f32_16x16x32_bf16(afr[1][0], bq[n][1], a0, 0, 0, 0);
        a1 = __builtin_amdgcn_mfma_f32_16x16x32_bf16(afr[1][1], bq[n][1], a1, 0, 0, 0);

        const f32x2 yy = {yv[n], yv[n]};
        const f32x2 d00 = __builtin_elementwise_fma(mm2, (f32x2){a0[0], a0[1]}, xq[0][0] + yy);
        const f32x2 d01 = __builtin_elementwise_fma(mm2, (f32x2){a0[2], a0[3]}, xq[0][1] + yy);
        const f32x2 d10 = __builtin_elementwise_fma(mm2, (f32x2){a1[0], a1[1]}, xq[1][0] + yy);
        const f32x2 d11 = __builtin_elementwise_fma(mm2, (f32x2){a1[2], a1[3]}, xq[1][1] + yy);
        rowm[0][0] = __builtin_elementwise_min(rowm[0][0], d00);
        rowm[0][1] = __builtin_elementwise_min(rowm[0][1], d01);
        rowm[1][0] = __builtin_elementwise_min(rowm[1][0], d10);
        rowm[1][1] = __builtin_elementwise_min(rowm[1][1], d11);
        const f32x2 cp = __builtin_elementwise_min(
                             __builtin_elementwise_min(d00, d01),
                             __builtin_elementwise_min(d10, d11));
        colm[n] = fminf(cp[0], cp[1]);
    }

    // ---- row partials: shfl-reduce over the 16 lr lanes, plain store
    float* rdst = rpart + ((size_t)(rb * ncb + cb)) * 128 + w * 32;
    #pragma unroll
    for (int m = 0; m < 2; ++m)
        #pragma unroll
        for (int jp = 0; jp < 2; ++jp)
            #pragma unroll
            for (int c = 0; c < 2; ++c) {
                float v = rowm[m][jp][c];
                v = fminf(v, __shfl_xor(v, 1));
                v = fminf(v, __shfl_xor(v, 2));
                v = fminf(v, __shfl_xor(v, 4));
                v = fminf(v, __shfl_xor(v, 8));
                if (lr == 0)
                    rdst[m * 16 + lh * 4 + jp * 2 + c] = fmaxf(v, 0.f);
            }

    // ---- col partials: shfl-reduce over the 4 lh groups; PER-WAVE slice
    float* cdst = cpart + ((size_t)(cb * nrb + rb)) * 512 + w * 128;
    #pragma unroll
    for (int n = 0; n < 8; ++n) {
        float c = colm[n];
        c = fminf(c, __shfl_xor(c, 16));
        c = fminf(c, __shfl_xor(c, 32));
        if (lh == 0)
            cdst[n * 16 + lr] = fmaxf(c, 0.f);
    }
}

// ---------------------------------------------------------------------------
// reduce: rows -- min over ncb partials; cols -- min over nrb*4 wave slices.
// Then sqrt + deterministic per-block partial sum.
// ---------------------------------------------------------------------------
__global__ __launch_bounds__(128) void ahd_reduce(
    const float* __restrict__ rpart, const float* __restrict__ cpart,
    float* __restrict__ bsum, int nrb, int ncb, int N, int M)
{
    const int bid = blockIdx.x;
    const int t   = threadIdx.x;
    float acc = 1e30f;
    if (bid < nrb) {
        const float* base = rpart + (size_t)bid * ncb * 128 + t;
        for (int cb = 0; cb < ncb; cb += 4) {
            float a0 = base[(size_t)(cb + 0) * 128];
            float a1 = base[(size_t)(cb + 1) * 128];
            float a2 = base[(size_t)(cb + 2) * 128];
            float a3 = base[(size_t)(cb + 3) * 128];
            acc = fminf(acc, fminf(fminf(a0, a1), fminf(a2, a3)));
        }
    } else {
        const int cb = bid - nrb;
        const float* base = cpart + (size_t)cb * nrb * 512 + t;
        for (int rb = 0; rb < nrb; ++rb) {
            const float* p = base + (size_t)rb * 512;
            float a0 = p[0], a1 = p[128], a2 = p[256], a3 = p[384];
            acc = fminf(acc, fminf(fminf(a0, a1), fminf(a2, a3)));
        }
    }
    float s = sqrtf(acc);
    s += __shfl_xor(s, 1);  s += __shfl_xor(s, 2);
    s += __shfl_xor(s, 4);  s += __shfl_xor(s, 8);
    s += __shfl_xor(s, 16); s += __shfl_xor(s, 32);
    __shared__ float red[2];
    if ((t & 63) == 0) red[t >> 6] = s;
    __syncthreads();
    if (t == 0) bsum[bid] = (red[0] + red[1]) * (bid < nrb ? 1.f / N : 1.f / M);
}

__global__ __launch_bounds__(256) void ahd_final(
    const float* __restrict__ bsum, float* __restrict__ out, int nb)
{
    const int t = threadIdx.x;
    float s = (t < nb) ? bsum[t] : 0.f;
    s += __shfl_xor(s, 1);  s += __shfl_xor(s, 2);
    s += __shfl_xor(s, 4);  s += __shfl_xor(s, 8);
    s += __shfl_xor(s, 16); s += __shfl_xor(s, 32);
    __shared__ float red[4];
    if ((t & 63) == 0) red[t >> 6] = s;
    __syncthreads();
    if (t == 0) out[0] = red[0] + red[1] + red[2] + red[3];
}

extern "C" void kernel_launch(void* const* d_in, const int* in_sizes, int n_in,
                              void* d_out, int out_size, void* d_ws, size_t ws_size,
                              hipStream_t stream) {
    const float* s1 = (const float*)d_in[0];
    const float* s2 = (const float*)d_in[1];
    const int N = in_sizes[0] / 64;
    const int M = in_sizes[1] / 64;
    const int nrb = N / 128, ncb = M / 128;

    char* ws = (char*)d_ws;
    __hip_bfloat16* abf = (__hip_bfloat16*)ws;                      // 2 MB
    __hip_bfloat16* bbf = (__hip_bfloat16*)(ws + (size_t)N * 128);  // 2 MB
    float* x2 = (float*)(ws + (size_t)(N + M) * 128);
    float* y2 = x2 + N;
    float* rpart = y2 + M;                                   // nrb*ncb*128  (8 MB)
    float* cpart = rpart + (size_t)nrb * ncb * 128;          // ncb*nrb*512 (32 MB)
    float* bsum  = cpart + (size_t)ncb * nrb * 512;          // nrb+ncb

    const int prows = ((N + M) * 16 + 255) / 256;
    ahd_prep<<<prows, 256, 0, stream>>>(s1, s2, abf, bbf, x2, y2, N, M);
    dim3 grid(nrb, ncb);
    ahd_gemm<<<grid, 256, 0, stream>>>(abf, bbf, x2, y2, rpart, cpart, nrb, ncb);
    ahd_reduce<<<nrb + ncb, 128, 0, stream>>>(rpart, cpart, bsum, nrb, ncb, N, M);
    ahd_final<<<1, 256, 0, stream>>>(bsum, (float*)d_out, nrb + ncb);
}

// Round 10
// 199.982 us; speedup vs baseline: 1.0029x; 1.0029x over previous
//
#include <hip/hip_runtime.h>
#include <hip/hip_bf16.h>

typedef __attribute__((ext_vector_type(8))) short short8;  // 8 bf16 (4 VGPRs)
typedef __attribute__((ext_vector_type(4))) short short4v;
typedef __attribute__((ext_vector_type(4))) float f32x4;

#define INF_BITS 0x7F800000u

// ---------------------------------------------------------------------------
// prep: fp32 -> bf16, h-norms (-0.5*||.||^2, fp32 exact), init min arrays.
// 16 lanes per row, float4 loads / 8B stores.
// ---------------------------------------------------------------------------
__global__ __launch_bounds__(256) void ahd_prep(
    const float* __restrict__ s1, const float* __restrict__ s2,
    __hip_bfloat16* __restrict__ abf, __hip_bfloat16* __restrict__ bbf,
    float* __restrict__ xh, float* __restrict__ yh,
    unsigned int* __restrict__ rmin, unsigned int* __restrict__ cmin,
    int N, int M)
{
    const int t   = blockIdx.x * 256 + threadIdx.x;
    const int row = t >> 4;
    const int sub = t & 15;

    if (t < N)          rmin[t]     = INF_BITS;
    else if (t < N + M) cmin[t - N] = INF_BITS;

    const float* src; __hip_bfloat16* dst; float* nrm; int r;
    if (row < N)            { src = s1; dst = abf; nrm = xh; r = row; }
    else if (row < N + M)   { src = s2; dst = bbf; nrm = yh; r = row - N; }
    else return;

    const float4 v = *(const float4*)&src[(size_t)r * 64 + sub * 4];
    __hip_bfloat16 h0 = __float2bfloat16(v.x), h1 = __float2bfloat16(v.y);
    __hip_bfloat16 h2 = __float2bfloat16(v.z), h3 = __float2bfloat16(v.w);
    short4v sv = { *(short*)&h0, *(short*)&h1, *(short*)&h2, *(short*)&h3 };
    *(short4v*)&dst[(size_t)r * 64 + sub * 4] = sv;

    float ss = v.x * v.x + v.y * v.y + v.z * v.z + v.w * v.w;
    ss += __shfl_xor(ss, 1);
    ss += __shfl_xor(ss, 2);
    ss += __shfl_xor(ss, 4);
    ss += __shfl_xor(ss, 8);
    if (sub == 0) nrm[r] = -0.5f * ss;     // fold: C-init = xh + yh
}

// ---------------------------------------------------------------------------
// fused distance-GEMM + row/col min via the C-INIT FOLD (round-9 lesson:
// ~14 VALU issue-slots per element across ALL prior structures; the add+2fma
// per-element epilogue was the invariant cost). Init MFMA C with
// -(x^2+y^2)/2 so acc = ab - (x^2+y^2)/2 and min d^2 == max acc:
// epilogue is ONE max3 per 2 elements (row) + max tree (col). No LDS staging,
// no in-loop barriers (LDS = 8KB colbuf only); A/B/y from L2 with depth-1
// register prefetch in a fully-unrolled, statically-indexed loop.
// Wave = 64 rows x 512 cols (16 tiles of 64x32); block = 4 waves = 256x512.
// ---------------------------------------------------------------------------
__global__ __launch_bounds__(256) void ahd_gemm(
    const __hip_bfloat16* __restrict__ abf, const __hip_bfloat16* __restrict__ bbf,
    const float* __restrict__ xh, const float* __restrict__ yh,
    unsigned int* __restrict__ rmin, unsigned int* __restrict__ cmin,
    int NRB, int nwg)
{
    __shared__ float colbuf[4][512];

    const int tid  = threadIdx.x;
    const int lane = tid & 63;
    const int w    = tid >> 6;
    const int lr   = lane & 15, lh = lane >> 4;

    // XCD-bijective swizzle (nwg % 8 == 0): consecutive swz share a B-strip
    const int bid = blockIdx.x;
    const int swz = (bid & 7) * (nwg >> 3) + (bid >> 3);
    const int brow  = (swz % NRB) * 256;
    const int bcol0 = (swz / NRB) * 512;
    const int wrow  = brow + w * 64;        // this wave's 64 rows

    // ---- A fragments straight from global (reused across all 16 tiles)
    const char* aB = (const char*)abf + (size_t)(wrow + lr) * 128 + lh * 16;
    short8 afr[2][4];
    #pragma unroll
    for (int ks = 0; ks < 2; ++ks)
        #pragma unroll
        for (int m = 0; m < 4; ++m)
            afr[ks][m] = *(const short8*)(aB + m * 2048 + ks * 64);

    // ---- xh in registers: xq[m][j] = -x^2/2 for row wrow+m*16+lh*4+j
    f32x4 xq[4];
    #pragma unroll
    for (int m = 0; m < 4; ++m)
        xq[m] = *(const f32x4*)&xh[wrow + m * 16 + lh * 4];

    float rowm[4][4];
    #pragma unroll
    for (int m = 0; m < 4; ++m)
        #pragma unroll
        for (int j = 0; j < 4; ++j) rowm[m][j] = -1e30f;   // MAX accumulator

    const char*  bB = (const char*)bbf + (size_t)(bcol0 + lr) * 128 + lh * 16;
    const float* yB = yh + bcol0 + lr;

    // process one 64x32 tile: cinit-adds -> 16 MFMA -> max3 epilogue
    auto process = [&](int ct, short8 (&bq)[4], float ya, float yb) {
        f32x4 acc[4][2];
        #pragma unroll
        for (int m = 0; m < 4; ++m)
            #pragma unroll
            for (int n = 0; n < 2; ++n) {
                const float yv = n ? yb : ya;
                f32x4 c;
                c[0] = xq[m][0] + yv;  c[1] = xq[m][1] + yv;
                c[2] = xq[m][2] + yv;  c[3] = xq[m][3] + yv;
                c = __builtin_amdgcn_mfma_f32_16x16x32_bf16(afr[0][m], bq[n * 2], c, 0, 0, 0);
                acc[m][n] = __builtin_amdgcn_mfma_f32_16x16x32_bf16(afr[1][m], bq[n * 2 + 1], c, 0, 0, 0);
            }
        // row path: one max3 per 2 elements
        #pragma unroll
        for (int m = 0; m < 4; ++m)
            #pragma unroll
            for (int j = 0; j < 4; ++j)
                rowm[m][j] = fmaxf(fmaxf(acc[m][0][j], acc[m][1][j]), rowm[m][j]);
        // col path: max tree over the 16 (m,j) slots per n
        float c0, c1;
        {
            const float t0 = fmaxf(fmaxf(acc[0][0][0], acc[0][0][1]), fmaxf(acc[0][0][2], acc[0][0][3]));
            const float t1 = fmaxf(fmaxf(acc[1][0][0], acc[1][0][1]), fmaxf(acc[1][0][2], acc[1][0][3]));
            const float t2 = fmaxf(fmaxf(acc[2][0][0], acc[2][0][1]), fmaxf(acc[2][0][2], acc[2][0][3]));
            const float t3 = fmaxf(fmaxf(acc[3][0][0], acc[3][0][1]), fmaxf(acc[3][0][2], acc[3][0][3]));
            c0 = fmaxf(fmaxf(t0, t1), fmaxf(t2, t3));
        }
        {
            const float t0 = fmaxf(fmaxf(acc[0][1][0], acc[0][1][1]), fmaxf(acc[0][1][2], acc[0][1][3]));
            const float t1 = fmaxf(fmaxf(acc[1][1][0], acc[1][1][1]), fmaxf(acc[1][1][2], acc[1][1][3]));
            const float t2 = fmaxf(fmaxf(acc[2][1][0], acc[2][1][1]), fmaxf(acc[2][1][2], acc[2][1][3]));
            const float t3 = fmaxf(fmaxf(acc[3][1][0], acc[3][1][1]), fmaxf(acc[3][1][2], acc[3][1][3]));
            c1 = fmaxf(fmaxf(t0, t1), fmaxf(t2, t3));
        }
        // cols live on 4 lh-copies -> 2 shuffle rounds; park in wave slice
        c0 = fmaxf(c0, __shfl_xor(c0, 16));
        c0 = fmaxf(c0, __shfl_xor(c0, 32));
        c1 = fmaxf(c1, __shfl_xor(c1, 16));
        c1 = fmaxf(c1, __shfl_xor(c1, 32));
        if (lh == 0) {
            colbuf[w][ct * 32 + lr]      = c0;
            colbuf[w][ct * 32 + 16 + lr] = c1;
        }
    };

    // ---- fully-unrolled strip loop, renamed double buffers (no rotation movs)
    short8 b0[4], b1[4];
    float ya0, yb0, ya1, yb1;
    #pragma unroll
    for (int q = 0; q < 4; ++q)
        b0[q] = *(const short8*)(bB + (q >> 1) * 2048 + (q & 1) * 64);
    ya0 = yB[0]; yb0 = yB[16];

    #pragma unroll
    for (int ct = 0; ct < 16; ct += 2) {
        {   // prefetch tile ct+1 into b1
            const char* bt = bB + (size_t)(ct + 1) * 4096;
            #pragma unroll
            for (int q = 0; q < 4; ++q)
                b1[q] = *(const short8*)(bt + (q >> 1) * 2048 + (q & 1) * 64);
            ya1 = yB[(ct + 1) * 32]; yb1 = yB[(ct + 1) * 32 + 16];
        }
        process(ct, b0, ya0, yb0);
        if (ct + 2 < 16) {   // prefetch tile ct+2 into b0
            const char* bt = bB + (size_t)(ct + 2) * 4096;
            #pragma unroll
            for (int q = 0; q < 4; ++q)
                b0[q] = *(const short8*)(bt + (q >> 1) * 2048 + (q & 1) * 64);
            ya0 = yB[(ct + 2) * 32]; yb0 = yB[(ct + 2) * 32 + 16];
        }
        process(ct + 1, b1, ya1, yb1);
    }

    // ---- row flush: 4 shuffle rounds across lr, d^2 = max(-2*acc, 0)
    #pragma unroll
    for (int m = 0; m < 4; ++m)
        #pragma unroll
        for (int j = 0; j < 4; ++j) {
            float v = rowm[m][j];
            v = fmaxf(v, __shfl_xor(v, 1));
            v = fmaxf(v, __shfl_xor(v, 2));
            v = fmaxf(v, __shfl_xor(v, 4));
            v = fmaxf(v, __shfl_xor(v, 8));
            if (lr == 0) {
                const int row = wrow + m * 16 + lh * 4 + j;
                const float d2 = fmaxf(-2.f * v, 0.f);
                atomicMin(&rmin[row], __float_as_uint(d2));
            }
        }

    __syncthreads();   // the only barrier: colbuf slices complete

    // ---- col flush: merge 4 wave slices, 2 cols per thread
    #pragma unroll
    for (int k = 0; k < 2; ++k) {
        const int c = tid * 2 + k;
        const float v = fmaxf(fmaxf(colbuf[0][c], colbuf[1][c]),
                              fmaxf(colbuf[2][c], colbuf[3][c]));
        const float d2 = fmaxf(-2.f * v, 0.f);
        atomicMin(&cmin[bcol0 + c], __float_as_uint(d2));
    }
}

// ---------------------------------------------------------------------------
// finalize: out = mean(sqrt(rmin)) + mean(sqrt(cmin)); 1024 thr, uint4 loads.
// ---------------------------------------------------------------------------
__global__ __launch_bounds__(1024) void ahd_finalize(
    const unsigned int* __restrict__ rmin, const unsigned int* __restrict__ cmin,
    float* __restrict__ out, int N, int M)
{
    const int tid = threadIdx.x;
    const uint4* r4 = (const uint4*)rmin;
    const uint4* c4 = (const uint4*)cmin;
    float sa = 0.f, sb = 0.f;
    for (int i = tid; i < (N >> 2); i += 1024) {
        const uint4 v = r4[i];
        sa += sqrtf(__uint_as_float(v.x)) + sqrtf(__uint_as_float(v.y))
            + sqrtf(__uint_as_float(v.z)) + sqrtf(__uint_as_float(v.w));
    }
    for (int i = tid; i < (M >> 2); i += 1024) {
        const uint4 v = c4[i];
        sb += sqrtf(__uint_as_float(v.x)) + sqrtf(__uint_as_float(v.y))
            + sqrtf(__uint_as_float(v.z)) + sqrtf(__uint_as_float(v.w));
    }
    float v = sa / (float)N + sb / (float)M;
    #pragma unroll
    for (int s = 1; s < 64; s <<= 1) v += __shfl_xor(v, s);
    __shared__ float red[16];
    if ((tid & 63) == 0) red[tid >> 6] = v;
    __syncthreads();
    if (tid == 0) {
        float t = 0.f;
        #pragma unroll
        for (int i = 0; i < 16; ++i) t += red[i];
        out[0] = t;
    }
}

extern "C" void kernel_launch(void* const* d_in, const int* in_sizes, int n_in,
                              void* d_out, int out_size, void* d_ws, size_t ws_size,
                              hipStream_t stream) {
    const float* s1 = (const float*)d_in[0];
    const float* s2 = (const float*)d_in[1];
    const int N = in_sizes[0] / 64;
    const int M = in_sizes[1] / 64;

    char* ws = (char*)d_ws;
    __hip_bfloat16* abf = (__hip_bfloat16*)ws;
    __hip_bfloat16* bbf = (__hip_bfloat16*)(ws + (size_t)N * 128);
    float* xh = (float*)(ws + (size_t)(N + M) * 128);
    float* yh = xh + N;
    unsigned int* rmin = (unsigned int*)(yh + M);
    unsigned int* cmin = rmin + N;

    const int prows = ((N + M) * 16 + 255) / 256;
    ahd_prep<<<prows, 256, 0, stream>>>(s1, s2, abf, bbf, xh, yh,
                                        rmin, cmin, N, M);
    const int NRB = N / 256;            // 64 row-blocks
    const int STRIPS = M / 512;         // 32 col-strips
    const int nwg = NRB * STRIPS;       // 2048 blocks
    ahd_gemm<<<nwg, 256, 0, stream>>>(abf, bbf, xh, yh, rmin, cmin, NRB, nwg);
    ahd_finalize<<<1, 1024, 0, stream>>>(rmin, cmin, (float*)d_out, N, M);
}

// Round 11
// 163.544 us; speedup vs baseline: 1.2264x; 1.2228x over previous
//
#include <hip/hip_runtime.h>
#include <hip/hip_bf16.h>

typedef __attribute__((ext_vector_type(8))) short short8;  // 8 bf16 (4 VGPRs)
typedef __attribute__((ext_vector_type(4))) short short4v;
typedef __attribute__((ext_vector_type(4))) float f32x4;

#define INF_BITS 0x7F800000u

// ---------------------------------------------------------------------------
// prep: fp32 -> bf16, h-norms (-0.5*||.||^2, fp32 exact), init min arrays.
// 16 lanes per row, float4 loads / 8B stores.
// ---------------------------------------------------------------------------
__global__ __launch_bounds__(256) void ahd_prep(
    const float* __restrict__ s1, const float* __restrict__ s2,
    __hip_bfloat16* __restrict__ abf, __hip_bfloat16* __restrict__ bbf,
    float* __restrict__ xh, float* __restrict__ yh,
    unsigned int* __restrict__ rmin, unsigned int* __restrict__ cmin,
    int N, int M)
{
    const int t   = blockIdx.x * 256 + threadIdx.x;
    const int row = t >> 4;
    const int sub = t & 15;

    if (t < N)          rmin[t]     = INF_BITS;
    else if (t < N + M) cmin[t - N] = INF_BITS;

    const float* src; __hip_bfloat16* dst; float* nrm; int r;
    if (row < N)            { src = s1; dst = abf; nrm = xh; r = row; }
    else if (row < N + M)   { src = s2; dst = bbf; nrm = yh; r = row - N; }
    else return;

    const float4 v = *(const float4*)&src[(size_t)r * 64 + sub * 4];
    __hip_bfloat16 h0 = __float2bfloat16(v.x), h1 = __float2bfloat16(v.y);
    __hip_bfloat16 h2 = __float2bfloat16(v.z), h3 = __float2bfloat16(v.w);
    short4v sv = { *(short*)&h0, *(short*)&h1, *(short*)&h2, *(short*)&h3 };
    *(short4v*)&dst[(size_t)r * 64 + sub * 4] = sv;

    float ss = v.x * v.x + v.y * v.y + v.z * v.z + v.w * v.w;
    ss += __shfl_xor(ss, 1);
    ss += __shfl_xor(ss, 2);
    ss += __shfl_xor(ss, 4);
    ss += __shfl_xor(ss, 8);
    if (sub == 0) nrm[r] = -0.5f * ss;     // fold: MFMA C-init = xh + yh
}

// ---------------------------------------------------------------------------
// fused distance-GEMM + row/col min via the C-INIT FOLD (proven correct in
// R10): acc = a.b - (x^2+y^2)/2 so min d^2 == max acc; epilogue is max3 ops
// only. Round-10 lesson: full unroll + lambda spilled to 256 VGPR. This
// round's design center is REGISTER DISCIPLINE: wave = 32 rows x 512-col
// strip (16 tiles of 32 cols), no prefetch buffers, no forced launch bounds,
// unroll 2, all-static indexing -> ~100 VGPR -> 4 waves/SIMD; latency is
// hidden by TLP (4 co-resident waves), not software pipelining. No LDS
// staging, no in-loop barriers. B/y straight from L2 (XCD-swizzled strips).
// ---------------------------------------------------------------------------
__global__ __launch_bounds__(256) void ahd_gemm(
    const __hip_bfloat16* __restrict__ abf, const __hip_bfloat16* __restrict__ bbf,
    const float* __restrict__ xh, const float* __restrict__ yh,
    unsigned int* __restrict__ rmin, unsigned int* __restrict__ cmin,
    int NRB, int nwg)
{
    __shared__ float colbuf[4][512];

    const int tid  = threadIdx.x;
    const int lane = tid & 63;
    const int w    = tid >> 6;
    const int lr   = lane & 15, lh = lane >> 4;

    // XCD-bijective swizzle (nwg % 8 == 0): each XCD works 4 B-strips
    const int bid = blockIdx.x;
    const int swz = (bid & 7) * (nwg >> 3) + (bid >> 3);
    const int brow  = (swz % NRB) * 128;
    const int bcol0 = (swz / NRB) * 512;
    const int wrow  = brow + w * 32;        // this wave's 32 rows

    // ---- A fragments from global (loaded once, reused for all 16 tiles)
    const char* aB = (const char*)abf + (size_t)(wrow + lr) * 128 + lh * 16;
    const short8 a00 = *(const short8*)(aB);             // ks=0, m=0
    const short8 a01 = *(const short8*)(aB + 64);        // ks=1, m=0
    const short8 a10 = *(const short8*)(aB + 2048);      // ks=0, m=1
    const short8 a11 = *(const short8*)(aB + 2048 + 64); // ks=1, m=1

    // ---- xh in registers: xq[m][j] = -x^2/2 for row wrow+m*16+lh*4+j
    const f32x4 xq0 = *(const f32x4*)&xh[wrow + lh * 4];
    const f32x4 xq1 = *(const f32x4*)&xh[wrow + 16 + lh * 4];

    f32x4 rowm0 = {-1e30f, -1e30f, -1e30f, -1e30f};   // MAX accumulators
    f32x4 rowm1 = {-1e30f, -1e30f, -1e30f, -1e30f};

    const char*  bB = (const char*)bbf + (size_t)(bcol0 + lr) * 128 + lh * 16;
    const float* yB = yh + bcol0 + lr;

    #pragma unroll 2
    for (int ct = 0; ct < 16; ++ct) {
        // ---- B fragments + y for this 32-col tile (L2-hot)
        const char* bp = bB + (size_t)ct * 4096;
        const short8 b00 = *(const short8*)(bp);              // n=0, ks=0
        const short8 b01 = *(const short8*)(bp + 64);         // n=0, ks=1
        const short8 b10 = *(const short8*)(bp + 2048);       // n=1, ks=0
        const short8 b11 = *(const short8*)(bp + 2048 + 64);  // n=1, ks=1
        const float ya = yB[ct * 32];
        const float yb = yB[ct * 32 + 16];

        // ---- C-init (the fold) + 8 MFMA
        f32x4 c00 = {xq0[0] + ya, xq0[1] + ya, xq0[2] + ya, xq0[3] + ya};
        f32x4 c01 = {xq0[0] + yb, xq0[1] + yb, xq0[2] + yb, xq0[3] + yb};
        f32x4 c10 = {xq1[0] + ya, xq1[1] + ya, xq1[2] + ya, xq1[3] + ya};
        f32x4 c11 = {xq1[0] + yb, xq1[1] + yb, xq1[2] + yb, xq1[3] + yb};

        c00 = __builtin_amdgcn_mfma_f32_16x16x32_bf16(a00, b00, c00, 0, 0, 0);
        c01 = __builtin_amdgcn_mfma_f32_16x16x32_bf16(a00, b10, c01, 0, 0, 0);
        c10 = __builtin_amdgcn_mfma_f32_16x16x32_bf16(a10, b00, c10, 0, 0, 0);
        c11 = __builtin_amdgcn_mfma_f32_16x16x32_bf16(a10, b10, c11, 0, 0, 0);
        c00 = __builtin_amdgcn_mfma_f32_16x16x32_bf16(a01, b01, c00, 0, 0, 0);
        c01 = __builtin_amdgcn_mfma_f32_16x16x32_bf16(a01, b11, c01, 0, 0, 0);
        c10 = __builtin_amdgcn_mfma_f32_16x16x32_bf16(a11, b01, c10, 0, 0, 0);
        c11 = __builtin_amdgcn_mfma_f32_16x16x32_bf16(a11, b11, c11, 0, 0, 0);

        // ---- row path: one max3 per (m,j) over the two n-frags
        rowm0[0] = fmaxf(fmaxf(c00[0], c01[0]), rowm0[0]);
        rowm0[1] = fmaxf(fmaxf(c00[1], c01[1]), rowm0[1]);
        rowm0[2] = fmaxf(fmaxf(c00[2], c01[2]), rowm0[2]);
        rowm0[3] = fmaxf(fmaxf(c00[3], c01[3]), rowm0[3]);
        rowm1[0] = fmaxf(fmaxf(c10[0], c11[0]), rowm1[0]);
        rowm1[1] = fmaxf(fmaxf(c10[1], c11[1]), rowm1[1]);
        rowm1[2] = fmaxf(fmaxf(c10[2], c11[2]), rowm1[2]);
        rowm1[3] = fmaxf(fmaxf(c10[3], c11[3]), rowm1[3]);

        // ---- col path: max tree over the 8 (m,j) slots per n
        float cm0 = fmaxf(fmaxf(fmaxf(c00[0], c00[1]), fmaxf(c00[2], c00[3])),
                          fmaxf(fmaxf(c10[0], c10[1]), fmaxf(c10[2], c10[3])));
        float cm1 = fmaxf(fmaxf(fmaxf(c01[0], c01[1]), fmaxf(c01[2], c01[3])),
                          fmaxf(fmaxf(c11[0], c11[1]), fmaxf(c11[2], c11[3])));
        cm0 = fmaxf(cm0, __shfl_xor(cm0, 16));
        cm0 = fmaxf(cm0, __shfl_xor(cm0, 32));
        cm1 = fmaxf(cm1, __shfl_xor(cm1, 16));
        cm1 = fmaxf(cm1, __shfl_xor(cm1, 32));
        if (lh == 0) {
            colbuf[w][ct * 32 + lr]      = cm0;
            colbuf[w][ct * 32 + 16 + lr] = cm1;
        }
    }

    // ---- row flush: 4 shuffle rounds across lr; d^2 = max(-2*acc, 0)
    #pragma unroll
    for (int m = 0; m < 2; ++m)
        #pragma unroll
        for (int j = 0; j < 4; ++j) {
            float v = m ? rowm1[j] : rowm0[j];
            v = fmaxf(v, __shfl_xor(v, 1));
            v = fmaxf(v, __shfl_xor(v, 2));
            v = fmaxf(v, __shfl_xor(v, 4));
            v = fmaxf(v, __shfl_xor(v, 8));
            if (lr == 0) {
                const int row = wrow + m * 16 + lh * 4 + j;
                const float d2 = fmaxf(-2.f * v, 0.f);
                atomicMin(&rmin[row], __float_as_uint(d2));
            }
        }

    __syncthreads();   // the only barrier: colbuf slices complete

    // ---- col flush: merge 4 wave slices, 2 cols per thread
    #pragma unroll
    for (int k = 0; k < 2; ++k) {
        const int c = tid * 2 + k;
        const float v = fmaxf(fmaxf(colbuf[0][c], colbuf[1][c]),
                              fmaxf(colbuf[2][c], colbuf[3][c]));
        const float d2 = fmaxf(-2.f * v, 0.f);
        atomicMin(&cmin[bcol0 + c], __float_as_uint(d2));
    }
}

// ---------------------------------------------------------------------------
// finalize: out = mean(sqrt(rmin)) + mean(sqrt(cmin)); 1024 thr, uint4 loads.
// ---------------------------------------------------------------------------
__global__ __launch_bounds__(1024) void ahd_finalize(
    const unsigned int* __restrict__ rmin, const unsigned int* __restrict__ cmin,
    float* __restrict__ out, int N, int M)
{
    const int tid = threadIdx.x;
    const uint4* r4 = (const uint4*)rmin;
    const uint4* c4 = (const uint4*)cmin;
    float sa = 0.f, sb = 0.f;
    for (int i = tid; i < (N >> 2); i += 1024) {
        const uint4 v = r4[i];
        sa += sqrtf(__uint_as_float(v.x)) + sqrtf(__uint_as_float(v.y))
            + sqrtf(__uint_as_float(v.z)) + sqrtf(__uint_as_float(v.w));
    }
    for (int i = tid; i < (M >> 2); i += 1024) {
        const uint4 v = c4[i];
        sb += sqrtf(__uint_as_float(v.x)) + sqrtf(__uint_as_float(v.y))
            + sqrtf(__uint_as_float(v.z)) + sqrtf(__uint_as_float(v.w));
    }
    float v = sa / (float)N + sb / (float)M;
    #pragma unroll
    for (int s = 1; s < 64; s <<= 1) v += __shfl_xor(v, s);
    __shared__ float red[16];
    if ((tid & 63) == 0) red[tid >> 6] = v;
    __syncthreads();
    if (tid == 0) {
        float t = 0.f;
        #pragma unroll
        for (int i = 0; i < 16; ++i) t += red[i];
        out[0] = t;
    }
}

extern "C" void kernel_launch(void* const* d_in, const int* in_sizes, int n_in,
                              void* d_out, int out_size, void* d_ws, size_t ws_size,
                              hipStream_t stream) {
    const float* s1 = (const float*)d_in[0];
    const float* s2 = (const float*)d_in[1];
    const int N = in_sizes[0] / 64;
    const int M = in_sizes[1] / 64;

    char* ws = (char*)d_ws;
    __hip_bfloat16* abf = (__hip_bfloat16*)ws;
    __hip_bfloat16* bbf = (__hip_bfloat16*)(ws + (size_t)N * 128);
    float* xh = (float*)(ws + (size_t)(N + M) * 128);
    float* yh = xh + N;
    unsigned int* rmin = (unsigned int*)(yh + M);
    unsigned int* cmin = rmin + N;

    const int prows = ((N + M) * 16 + 255) / 256;
    ahd_prep<<<prows, 256, 0, stream>>>(s1, s2, abf, bbf, xh, yh,
                                        rmin, cmin, N, M);
    const int NRB = N / 128;            // 128 row-blocks
    const int STRIPS = M / 512;         // 32 col-strips
    const int nwg = NRB * STRIPS;       // 4096 blocks
    ahd_gemm<<<nwg, 256, 0, stream>>>(abf, bbf, xh, yh, rmin, cmin, NRB, nwg);
    ahd_finalize<<<1, 1024, 0, stream>>>(rmin, cmin, (float*)d_out, N, M);
}

// Round 12
// 100.235 us; speedup vs baseline: 2.0010x; 1.6316x over previous
//
#include <hip/hip_runtime.h>
#include <hip/hip_bf16.h>

typedef __attribute__((ext_vector_type(8))) short short8;  // 8 bf16 (4 VGPRs)
typedef __attribute__((ext_vector_type(4))) short short4v;
typedef __attribute__((ext_vector_type(4))) float f32x4;

#define INF_BITS 0x7F800000u

// ---------------------------------------------------------------------------
// prep: fp32 -> bf16, h-norms (-0.5*||.||^2, fp32 exact), init min arrays.
// ---------------------------------------------------------------------------
__global__ __launch_bounds__(256) void ahd_prep(
    const float* __restrict__ s1, const float* __restrict__ s2,
    __hip_bfloat16* __restrict__ abf, __hip_bfloat16* __restrict__ bbf,
    float* __restrict__ xh, float* __restrict__ yh,
    unsigned int* __restrict__ rmin, unsigned int* __restrict__ cmin,
    int N, int M)
{
    const int t   = blockIdx.x * 256 + threadIdx.x;
    const int row = t >> 4;
    const int sub = t & 15;

    if (t < N)          rmin[t]     = INF_BITS;
    else if (t < N + M) cmin[t - N] = INF_BITS;

    const float* src; __hip_bfloat16* dst; float* nrm; int r;
    if (row < N)            { src = s1; dst = abf; nrm = xh; r = row; }
    else if (row < N + M)   { src = s2; dst = bbf; nrm = yh; r = row - N; }
    else return;

    const float4 v = *(const float4*)&src[(size_t)r * 64 + sub * 4];
    __hip_bfloat16 h0 = __float2bfloat16(v.x), h1 = __float2bfloat16(v.y);
    __hip_bfloat16 h2 = __float2bfloat16(v.z), h3 = __float2bfloat16(v.w);
    short4v sv = { *(short*)&h0, *(short*)&h1, *(short*)&h2, *(short*)&h3 };
    *(short4v*)&dst[(size_t)r * 64 + sub * 4] = sv;

    float ss = v.x * v.x + v.y * v.y + v.z * v.z + v.w * v.w;
    ss += __shfl_xor(ss, 1);
    ss += __shfl_xor(ss, 2);
    ss += __shfl_xor(ss, 4);
    ss += __shfl_xor(ss, 8);
    if (sub == 0) nrm[r] = -0.5f * ss;     // fold: MFMA C-init = xh + yh
}

// ---------------------------------------------------------------------------
// fused distance-GEMM + row/col min = R1's memory skeleton (the only sub-120us
// structure: per-block B dedup via global_load_lds + 2D grid with NO XCD
// swizzle, spreading strip-broadcasts over all 8 L2s) + R10/R11's C-INIT FOLD
// (acc = a.b - (x^2+y^2)/2 -> min d^2 == max acc; epilogue = max3 trees only).
// Round-11 lesson: per-wave redundant B loads concentrated on one L2 = same-
// line service hotspot, ~97% stall at <30% pipe busy. Block = 128x128 tile,
// 4 waves 4x1 (rows wave-exclusive -> direct row atomics, no LDS row merge);
// 4 manually-expanded col-tile blocks, transient acc, ONE barrier.
// ---------------------------------------------------------------------------
__global__ __launch_bounds__(256) void ahd_gemm(
    const __hip_bfloat16* __restrict__ abf, const __hip_bfloat16* __restrict__ bbf,
    const float* __restrict__ xh, const float* __restrict__ yh,
    unsigned int* __restrict__ rmin, unsigned int* __restrict__ cmin)
{
    __shared__ __attribute__((aligned(128))) char ldsA[16384];
    __shared__ __attribute__((aligned(128))) char ldsB[16384];
    __shared__ float colbuf[4][128];

    const int tid  = threadIdx.x;
    const int lane = tid & 63;
    const int w    = tid >> 6;
    const int lr   = lane & 15, lh = lane >> 4;

    const int brow = blockIdx.x * 128;
    const int bcol = blockIdx.y * 128;

    // ---- stage A+B (16 KB each): linear LDS dest + inverse-swizzled source
    const char* aT = (const char*)abf + (size_t)brow * 128;
    const char* bT = (const char*)bbf + (size_t)bcol * 128;
    #pragma unroll
    for (int it = 0; it < 4; ++it) {
        const int dst = w * 1024 + it * 4096;
        const int o   = dst + lane * 16;
        const int so  = o ^ ((o >> 3) & 0x70);
        __builtin_amdgcn_global_load_lds(
            (const __attribute__((address_space(1))) void*)(aT + so),
            (__attribute__((address_space(3))) void*)(ldsA + dst), 16, 0, 0);
        __builtin_amdgcn_global_load_lds(
            (const __attribute__((address_space(1))) void*)(bT + so),
            (__attribute__((address_space(3))) void*)(ldsB + dst), 16, 0, 0);
    }

    // ---- norms into named regs while staging is in flight
    const f32x4 xq0 = *(const f32x4*)&xh[brow + w * 32 + lh * 4];
    const f32x4 xq1 = *(const f32x4*)&xh[brow + w * 32 + 16 + lh * 4];
    const float yv0 = yh[bcol + lr];
    const float yv1 = yh[bcol + 16 + lr];
    const float yv2 = yh[bcol + 32 + lr];
    const float yv3 = yh[bcol + 48 + lr];
    const float yv4 = yh[bcol + 64 + lr];
    const float yv5 = yh[bcol + 80 + lr];
    const float yv6 = yh[bcol + 96 + lr];
    const float yv7 = yh[bcol + 112 + lr];

    __syncthreads();   // drains staging; the ONLY barrier

    // ---- A fragments (this wave's 32 rows): [ks][m], swizzled reads
    short8 aK0M0, aK1M0, aK0M1, aK1M1;
    {
        int o;
        o = (w * 32 + lr) * 128 + lh * 16;            o ^= (o >> 3) & 0x70; aK0M0 = *(const short8*)(ldsA + o);
        o = (w * 32 + lr) * 128 + 64 + lh * 16;       o ^= (o >> 3) & 0x70; aK1M0 = *(const short8*)(ldsA + o);
        o = (w * 32 + 16 + lr) * 128 + lh * 16;       o ^= (o >> 3) & 0x70; aK0M1 = *(const short8*)(ldsA + o);
        o = (w * 32 + 16 + lr) * 128 + 64 + lh * 16;  o ^= (o >> 3) & 0x70; aK1M1 = *(const short8*)(ldsA + o);
    }

    f32x4 rowm0 = {-1e30f, -1e30f, -1e30f, -1e30f};   // MAX accumulators
    f32x4 rowm1 = {-1e30f, -1e30f, -1e30f, -1e30f};

    // one 32-col tile: n-pair (N0, N0+1); all offsets compile-time static
#define AHD_TILE(N0, YA, YB)                                                   \
    {                                                                          \
        int o00 = ((N0) * 16 + lr) * 128 + lh * 16;        o00 ^= (o00 >> 3) & 0x70; \
        int o01 = ((N0) * 16 + lr) * 128 + 64 + lh * 16;   o01 ^= (o01 >> 3) & 0x70; \
        int o10 = ((N0) * 16 + 16 + lr) * 128 + lh * 16;      o10 ^= (o10 >> 3) & 0x70; \
        int o11 = ((N0) * 16 + 16 + lr) * 128 + 64 + lh * 16; o11 ^= (o11 >> 3) & 0x70; \
        const short8 b00 = *(const short8*)(ldsB + o00);                       \
        const short8 b01 = *(const short8*)(ldsB + o01);                       \
        const short8 b10 = *(const short8*)(ldsB + o10);                       \
        const short8 b11 = *(const short8*)(ldsB + o11);                       \
        f32x4 c00 = {xq0[0] + (YA), xq0[1] + (YA), xq0[2] + (YA), xq0[3] + (YA)}; \
        f32x4 c01 = {xq0[0] + (YB), xq0[1] + (YB), xq0[2] + (YB), xq0[3] + (YB)}; \
        f32x4 c10 = {xq1[0] + (YA), xq1[1] + (YA), xq1[2] + (YA), xq1[3] + (YA)}; \
        f32x4 c11 = {xq1[0] + (YB), xq1[1] + (YB), xq1[2] + (YB), xq1[3] + (YB)}; \
        c00 = __builtin_amdgcn_mfma_f32_16x16x32_bf16(aK0M0, b00, c00, 0, 0, 0); \
        c01 = __builtin_amdgcn_mfma_f32_16x16x32_bf16(aK0M0, b10, c01, 0, 0, 0); \
        c10 = __builtin_amdgcn_mfma_f32_16x16x32_bf16(aK0M1, b00, c10, 0, 0, 0); \
        c11 = __builtin_amdgcn_mfma_f32_16x16x32_bf16(aK0M1, b10, c11, 0, 0, 0); \
        c00 = __builtin_amdgcn_mfma_f32_16x16x32_bf16(aK1M0, b01, c00, 0, 0, 0); \
        c01 = __builtin_amdgcn_mfma_f32_16x16x32_bf16(aK1M0, b11, c01, 0, 0, 0); \
        c10 = __builtin_amdgcn_mfma_f32_16x16x32_bf16(aK1M1, b01, c10, 0, 0, 0); \
        c11 = __builtin_amdgcn_mfma_f32_16x16x32_bf16(aK1M1, b11, c11, 0, 0, 0); \
        rowm0[0] = fmaxf(fmaxf(c00[0], c01[0]), rowm0[0]);                     \
        rowm0[1] = fmaxf(fmaxf(c00[1], c01[1]), rowm0[1]);                     \
        rowm0[2] = fmaxf(fmaxf(c00[2], c01[2]), rowm0[2]);                     \
        rowm0[3] = fmaxf(fmaxf(c00[3], c01[3]), rowm0[3]);                     \
        rowm1[0] = fmaxf(fmaxf(c10[0], c11[0]), rowm1[0]);                     \
        rowm1[1] = fmaxf(fmaxf(c10[1], c11[1]), rowm1[1]);                     \
        rowm1[2] = fmaxf(fmaxf(c10[2], c11[2]), rowm1[2]);                     \
        rowm1[3] = fmaxf(fmaxf(c10[3], c11[3]), rowm1[3]);                     \
        float cm0 = fmaxf(fmaxf(fmaxf(c00[0], c00[1]), fmaxf(c00[2], c00[3])), \
                          fmaxf(fmaxf(c10[0], c10[1]), fmaxf(c10[2], c10[3]))); \
        float cm1 = fmaxf(fmaxf(fmaxf(c01[0], c01[1]), fmaxf(c01[2], c01[3])), \
                          fmaxf(fmaxf(c11[0], c11[1]), fmaxf(c11[2], c11[3]))); \
        cm0 = fmaxf(cm0, __shfl_xor(cm0, 16));                                 \
        cm0 = fmaxf(cm0, __shfl_xor(cm0, 32));                                 \
        cm1 = fmaxf(cm1, __shfl_xor(cm1, 16));                                 \
        cm1 = fmaxf(cm1, __shfl_xor(cm1, 32));                                 \
        if (lh == 0) {                                                         \
            colbuf[w][(N0) * 16 + lr]      = cm0;                              \
            colbuf[w][(N0) * 16 + 16 + lr] = cm1;                              \
        }                                                                      \
    }

    AHD_TILE(0, yv0, yv1)
    AHD_TILE(2, yv2, yv3)
    AHD_TILE(4, yv4, yv5)
    AHD_TILE(6, yv6, yv7)
#undef AHD_TILE

    // ---- row flush: rows wave-exclusive; reduce across the 16 lr lanes
    #pragma unroll
    for (int m = 0; m < 2; ++m)
        #pragma unroll
        for (int j = 0; j < 4; ++j) {
            float v = m ? rowm1[j] : rowm0[j];
            v = fmaxf(v, __shfl_xor(v, 1));
            v = fmaxf(v, __shfl_xor(v, 2));
            v = fmaxf(v, __shfl_xor(v, 4));
            v = fmaxf(v, __shfl_xor(v, 8));
            if (lr == 0) {
                const int row = brow + w * 32 + m * 16 + lh * 4 + j;
                const float d2 = fmaxf(-2.f * v, 0.f);
                atomicMin(&rmin[row], __float_as_uint(d2));   // fire-and-forget
            }
        }

    __syncthreads();   // colbuf slices complete

    // ---- col flush: merge the 4 wave slices, 1 col per thread (tid<128)
    if (tid < 128) {
        const float v = fmaxf(fmaxf(colbuf[0][tid], colbuf[1][tid]),
                              fmaxf(colbuf[2][tid], colbuf[3][tid]));
        const float d2 = fmaxf(-2.f * v, 0.f);
        atomicMin(&cmin[bcol + tid], __float_as_uint(d2));
    }
}

// ---------------------------------------------------------------------------
// finalize: out = mean(sqrt(rmin)) + mean(sqrt(cmin)); 1024 thr, uint4 loads.
// ---------------------------------------------------------------------------
__global__ __launch_bounds__(1024) void ahd_finalize(
    const unsigned int* __restrict__ rmin, const unsigned int* __restrict__ cmin,
    float* __restrict__ out, int N, int M)
{
    const int tid = threadIdx.x;
    const uint4* r4 = (const uint4*)rmin;
    const uint4* c4 = (const uint4*)cmin;
    float sa = 0.f, sb = 0.f;
    for (int i = tid; i < (N >> 2); i += 1024) {
        const uint4 v = r4[i];
        sa += sqrtf(__uint_as_float(v.x)) + sqrtf(__uint_as_float(v.y))
            + sqrtf(__uint_as_float(v.z)) + sqrtf(__uint_as_float(v.w));
    }
    for (int i = tid; i < (M >> 2); i += 1024) {
        const uint4 v = c4[i];
        sb += sqrtf(__uint_as_float(v.x)) + sqrtf(__uint_as_float(v.y))
            + sqrtf(__uint_as_float(v.z)) + sqrtf(__uint_as_float(v.w));
    }
    float v = sa / (float)N + sb / (float)M;
    #pragma unroll
    for (int s = 1; s < 64; s <<= 1) v += __shfl_xor(v, s);
    __shared__ float red[16];
    if ((tid & 63) == 0) red[tid >> 6] = v;
    __syncthreads();
    if (tid == 0) {
        float t = 0.f;
        #pragma unroll
        for (int i = 0; i < 16; ++i) t += red[i];
        out[0] = t;
    }
}

extern "C" void kernel_launch(void* const* d_in, const int* in_sizes, int n_in,
                              void* d_out, int out_size, void* d_ws, size_t ws_size,
                              hipStream_t stream) {
    const float* s1 = (const float*)d_in[0];
    const float* s2 = (const float*)d_in[1];
    const int N = in_sizes[0] / 64;
    const int M = in_sizes[1] / 64;

    char* ws = (char*)d_ws;
    __hip_bfloat16* abf = (__hip_bfloat16*)ws;
    __hip_bfloat16* bbf = (__hip_bfloat16*)(ws + (size_t)N * 128);
    float* xh = (float*)(ws + (size_t)(N + M) * 128);
    float* yh = xh + N;
    unsigned int* rmin = (unsigned int*)(yh + M);
    unsigned int* cmin = rmin + N;

    const int prows = ((N + M) * 16 + 255) / 256;
    ahd_prep<<<prows, 256, 0, stream>>>(s1, s2, abf, bbf, xh, yh,
                                        rmin, cmin, N, M);
    dim3 grid(N / 128, M / 128);    // x = row-tiles fastest; NO XCD swizzle
    ahd_gemm<<<grid, 256, 0, stream>>>(abf, bbf, xh, yh, rmin, cmin);
    ahd_finalize<<<1, 1024, 0, stream>>>(rmin, cmin, (float*)d_out, N, M);
}